// Round 1
// baseline (1970.675 us; speedup 1.0000x reference)
//
#include <hip/hip_runtime.h>

static constexpr int C_ = 128, H_ = 128, W_ = 128;
static constexpr int HW_ = H_ * W_;
static constexpr int CHW_ = C_ * HW_;

__device__ __forceinline__ unsigned short f2b(float f) {
  union { float f; unsigned u; } cv; cv.f = f;
  unsigned r = cv.u + 0x7FFFu + ((cv.u >> 16) & 1u);
  return (unsigned short)(r >> 16);
}
__device__ __forceinline__ float b2f(unsigned short h) {
  union { unsigned u; float f; } cv; cv.u = ((unsigned)h) << 16;
  return cv.f;
}

// ---------------- K1: per-(b, channel-of-concat) mean sums ----------------
__global__ __launch_bounds__(256) void k_pool(const float* __restrict__ x,
                                              const float* __restrict__ y,
                                              float* __restrict__ sums) {
  int blk = blockIdx.x;              // 0..2047 = b*256 + c
  int b = blk >> 8, c = blk & 255;
  const float* src = (c < C_) ? (x + (size_t)b * CHW_ + (size_t)c * HW_)
                              : (y + (size_t)b * CHW_ + (size_t)(c - C_) * HW_);
  const float4* s4 = (const float4*)src;
  float acc = 0.f;
  for (int i = threadIdx.x; i < HW_ / 4; i += 256) {
    float4 v = s4[i];
    acc += v.x + v.y + v.z + v.w;
  }
  for (int off = 32; off; off >>= 1) acc += __shfl_down(acc, off, 64);
  __shared__ float red[4];
  int lane = threadIdx.x & 63, wv = threadIdx.x >> 6;
  if (lane == 0) red[wv] = acc;
  __syncthreads();
  if (threadIdx.x == 0) sums[blk] = red[0] + red[1] + red[2] + red[3];
}

// ---------------- K2: channel attention (squeeze-excite) ----------------
__global__ __launch_bounds__(256) void k_ca(const float* __restrict__ sums,
                                            const float* __restrict__ w1,
                                            const float* __restrict__ b1,
                                            const float* __restrict__ w2,
                                            const float* __restrict__ b2,
                                            float* __restrict__ ca) {
  int b = blockIdx.x;
  __shared__ float pooled[256];
  __shared__ float hb[16];
  int t = threadIdx.x;
  pooled[t] = sums[b * 256 + t] * (1.f / 16384.f);
  __syncthreads();
  if (t < 16) {
    float s = b1[t];
    for (int j = 0; j < 256; ++j) s += w1[t * 256 + j] * pooled[j];
    hb[t] = fmaxf(s, 0.f);
  }
  __syncthreads();
  float s = b2[t];
  for (int r = 0; r < 16; ++r) s += w2[t * 16 + r] * hb[r];
  ca[b * 256 + t] = 1.f / (1.f + __expf(-s));
}

// ---------------- K3: fold final_w[:,256:384] through proj pointwise ----------------
__global__ __launch_bounds__(128) void k_wc(const float* __restrict__ fw,
                                            const float* __restrict__ fb,
                                            const float* __restrict__ pw,
                                            const float* __restrict__ pb,
                                            float* __restrict__ Wc,
                                            float* __restrict__ bc) {
  int o = blockIdx.x, c = threadIdx.x;
  float acc = 0.f;
  for (int m = 0; m < 128; ++m) acc += fw[o * 384 + 256 + m] * pw[m * 128 + c];
  Wc[o * 128 + c] = acc;
  if (c == 0) {
    float a = fb[o];
    for (int m = 0; m < 128; ++m) a += fw[o * 384 + 256 + m] * pb[m];
    bc[o] = a;
  }
}

// ---------------- K4: fused dw+pw q/k/v + window attention ----------------
// grid 2048 = b(8) x 16x16 tiles of 8x8 spatial positions; 512 threads.
__global__ __launch_bounds__(512) void k_qkv_attn(
    const float* __restrict__ x, const float* __restrict__ y,
    const float* __restrict__ cab,
    const float* __restrict__ qdw, const float* __restrict__ qdb,
    const float* __restrict__ qpw, const float* __restrict__ qpb,
    const float* __restrict__ kdw, const float* __restrict__ kdb,
    const float* __restrict__ kpw, const float* __restrict__ kpb,
    const float* __restrict__ vdw, const float* __restrict__ vdb,
    const float* __restrict__ vpw, const float* __restrict__ vpb,
    unsigned short* __restrict__ outb) {
  __shared__ float A1[64][129];                  // 33 KB (dw outputs, f32)
  __shared__ float A2[64][129];                  // 33 KB
  __shared__ __align__(16) char ubuf[33024];     // halo(25.6K) / W(33K) / out-stage(33K)
  __shared__ unsigned short qs[64][129];         // 16.5 KB each, bf16
  __shared__ unsigned short ks[64][129];
  __shared__ unsigned short vs[64][129];

  unsigned short (*halo)[100] = (unsigned short(*)[100])ubuf;
  unsigned short (*Wt)[129]   = (unsigned short(*)[129])ubuf;
  float (*fst)[129]           = (float(*)[129])ubuf;

  const int t = threadIdx.x;
  const int blk = blockIdx.x;
  const int b = blk >> 8;
  const int tr = blk & 255;
  const int y0 = (tr >> 4) << 3;
  const int x0 = (tr & 15) << 3;
  const int og = t & 31;   // och = og + 32*j
  const int pg = t >> 5;   // pos = pg*4 + i

  auto load_halo = [&](const float* src) {
    for (int idx = t; idx < 12800; idx += 512) {
      int c = idx / 100;
      int r = idx - c * 100;
      int hy = r / 10, hx = r - hy * 10;
      int gy = y0 - 1 + hy, gx = x0 - 1 + hx;
      float v = 0.f;
      if ((unsigned)gy < 128u && (unsigned)gx < 128u)
        v = src[(size_t)c * HW_ + gy * W_ + gx];
      halo[c][r] = f2b(v);
    }
  };
  auto dw_into = [&](const float* wdw, const float* bdw, const float* cas,
                     float (*A)[129]) {
    for (int o = t; o < 8192; o += 512) {
      int c = o >> 6, pos = o & 63;
      int py = pos >> 3, px = pos & 7;
      const float* wp = wdw + c * 9;
      const unsigned short* h0 = &halo[c][py * 10 + px];
      float s = b2f(h0[0]) * wp[0] + b2f(h0[1]) * wp[1] + b2f(h0[2]) * wp[2]
              + b2f(h0[10]) * wp[3] + b2f(h0[11]) * wp[4] + b2f(h0[12]) * wp[5]
              + b2f(h0[20]) * wp[6] + b2f(h0[21]) * wp[7] + b2f(h0[22]) * wp[8];
      A[pos][c] = s * cas[c] + bdw[c];
    }
  };
  auto load_w = [&](const float* wsrc) {
    for (int idx = t; idx < 16384; idx += 512)
      Wt[idx >> 7][idx & 127] = f2b(wsrc[idx]);
  };
  auto gemm_store = [&](const float (*A)[129], const float* bias,
                        unsigned short (*dst)[129]) {
    float acc[4][4];
    #pragma unroll
    for (int i = 0; i < 4; ++i)
      #pragma unroll
      for (int j = 0; j < 4; ++j) acc[i][j] = 0.f;
    #pragma unroll 4
    for (int c = 0; c < 128; ++c) {
      float av[4];
      #pragma unroll
      for (int i = 0; i < 4; ++i) av[i] = A[pg * 4 + i][c];
      #pragma unroll
      for (int j = 0; j < 4; ++j) {
        float w = b2f(Wt[og + 32 * j][c]);
        #pragma unroll
        for (int i = 0; i < 4; ++i) acc[i][j] = fmaf(av[i], w, acc[i][j]);
      }
    }
    #pragma unroll
    for (int j = 0; j < 4; ++j) {
      int och = og + 32 * j;
      float bv = bias[och];
      #pragma unroll
      for (int i = 0; i < 4; ++i) dst[pg * 4 + i][och] = f2b(acc[i][j] + bv);
    }
  };

  const float* cax = cab + b * 256;        // scales for x_att (k, v)
  const float* cay = cax + 128;            // scales for y_att (q)

  load_halo(y + (size_t)b * CHW_);
  __syncthreads();
  dw_into(qdw, qdb, cay, A1);
  __syncthreads();
  load_w(qpw);
  __syncthreads();
  gemm_store(A1, qpb, qs);
  __syncthreads();
  load_halo(x + (size_t)b * CHW_);
  __syncthreads();
  dw_into(kdw, kdb, cax, A1);
  dw_into(vdw, vdb, cax, A2);
  __syncthreads();
  load_w(kpw);
  __syncthreads();
  gemm_store(A1, kpb, ks);
  __syncthreads();
  load_w(vpw);
  __syncthreads();
  gemm_store(A2, vpb, vs);
  __syncthreads();

  // ---- window attention: 4 windows x 8 heads x 16 q-rows = 512 tasks
  {
    int wi = t >> 7;
    int h8 = (t >> 4) & 7;
    int n  = t & 15;
    int wy = (wi >> 1) << 2, wx = (wi & 1) << 2;
    int qpos = (wy + (n >> 2)) * 8 + wx + (n & 3);
    int co = h8 * 16;
    float qv[16];
    #pragma unroll
    for (int d = 0; d < 16; ++d) qv[d] = b2f(qs[qpos][co + d]);
    float sc[16];
    float m = -1e30f;
    #pragma unroll
    for (int jj = 0; jj < 16; ++jj) {
      int kpos = (wy + (jj >> 2)) * 8 + wx + (jj & 3);
      float s = 0.f;
      #pragma unroll
      for (int d = 0; d < 16; ++d) s = fmaf(qv[d], b2f(ks[kpos][co + d]), s);
      s *= 0.25f;
      sc[jj] = s;
      m = fmaxf(m, s);
    }
    float l = 0.f;
    #pragma unroll
    for (int jj = 0; jj < 16; ++jj) { float e = __expf(sc[jj] - m); sc[jj] = e; l += e; }
    float rl = 1.f / l;
    float ov[16];
    #pragma unroll
    for (int d = 0; d < 16; ++d) ov[d] = 0.f;
    #pragma unroll
    for (int jj = 0; jj < 16; ++jj) {
      int vpos = (wy + (jj >> 2)) * 8 + wx + (jj & 3);
      float p = sc[jj] * rl;
      #pragma unroll
      for (int d = 0; d < 16; ++d) ov[d] = fmaf(p, b2f(vs[vpos][co + d]), ov[d]);
    }
    #pragma unroll
    for (int d = 0; d < 16; ++d) fst[qpos][co + d] = ov[d];
  }
  __syncthreads();
  {
    unsigned short* dst = outb + (size_t)b * CHW_;
    for (int idx = t; idx < 8192; idx += 512) {
      int c = idx >> 6, pos = idx & 63;
      dst[(size_t)c * HW_ + (y0 + (pos >> 3)) * W_ + x0 + (pos & 7)] = f2b(fst[pos][c]);
    }
  }
}

// ---------------- K5: proj-dw + folded final GEMMs + BN + ReLU ----------------
__global__ __launch_bounds__(512) void k_final(
    const float* __restrict__ x, const float* __restrict__ y,
    const float* __restrict__ cab,
    const unsigned short* __restrict__ outb,
    const float* __restrict__ pdw, const float* __restrict__ pdb,
    const float* __restrict__ Wc, const float* __restrict__ bc,
    const float* __restrict__ fw,
    const float* __restrict__ bng, const float* __restrict__ bnb,
    const float* __restrict__ bnm, const float* __restrict__ bnv,
    float* __restrict__ outp) {
  __shared__ float A[64][129];
  __shared__ __align__(16) char ubuf[33024];
  unsigned short (*halo)[100] = (unsigned short(*)[100])ubuf;
  unsigned short (*Wt)[129]   = (unsigned short(*)[129])ubuf;
  float (*fst)[129]           = (float(*)[129])ubuf;

  const int t = threadIdx.x;
  const int blk = blockIdx.x;
  const int b = blk >> 8;
  const int tr = blk & 255;
  const int y0 = (tr >> 4) << 3;
  const int x0 = (tr & 15) << 3;
  const int og = t & 31;
  const int pg = t >> 5;

  float acc[4][4];
  #pragma unroll
  for (int i = 0; i < 4; ++i)
    #pragma unroll
    for (int j = 0; j < 4; ++j) acc[i][j] = 0.f;

  auto gemm_acc = [&]() {
    #pragma unroll 4
    for (int c = 0; c < 128; ++c) {
      float av[4];
      #pragma unroll
      for (int i = 0; i < 4; ++i) av[i] = A[pg * 4 + i][c];
      #pragma unroll
      for (int j = 0; j < 4; ++j) {
        float w = b2f(Wt[og + 32 * j][c]);
        #pragma unroll
        for (int i = 0; i < 4; ++i) acc[i][j] = fmaf(av[i], w, acc[i][j]);
      }
    }
  };

  // stage 1: proj depthwise on attention output (bf16 halo from ws)
  {
    const unsigned short* src = outb + (size_t)b * CHW_;
    for (int idx = t; idx < 12800; idx += 512) {
      int c = idx / 100;
      int r = idx - c * 100;
      int hy = r / 10, hx = r - hy * 10;
      int gy = y0 - 1 + hy, gx = x0 - 1 + hx;
      unsigned short v = 0;
      if ((unsigned)gy < 128u && (unsigned)gx < 128u)
        v = src[(size_t)c * HW_ + gy * W_ + gx];
      halo[c][r] = v;
    }
  }
  __syncthreads();
  for (int o = t; o < 8192; o += 512) {
    int c = o >> 6, pos = o & 63;
    int py = pos >> 3, px = pos & 7;
    const float* wp = pdw + c * 9;
    const unsigned short* h0 = &halo[c][py * 10 + px];
    float s = b2f(h0[0]) * wp[0] + b2f(h0[1]) * wp[1] + b2f(h0[2]) * wp[2]
            + b2f(h0[10]) * wp[3] + b2f(h0[11]) * wp[4] + b2f(h0[12]) * wp[5]
            + b2f(h0[20]) * wp[6] + b2f(h0[21]) * wp[7] + b2f(h0[22]) * wp[8];
    A[pos][c] = s + pdb[c];
  }
  __syncthreads();
  for (int idx = t; idx < 16384; idx += 512)
    Wt[idx >> 7][idx & 127] = f2b(Wc[idx]);
  __syncthreads();
  gemm_acc();
  __syncthreads();

  // stage 2: element_wise = x*y  through final_w[:, 0:128]
  for (int o = t; o < 8192; o += 512) {
    int c = o >> 6, pos = o & 63;
    size_t g = (size_t)b * CHW_ + (size_t)c * HW_ + (y0 + (pos >> 3)) * W_ + x0 + (pos & 7);
    A[pos][c] = x[g] * y[g];
  }
  for (int idx = t; idx < 16384; idx += 512) {
    int o2 = idx >> 7, c2 = idx & 127;
    Wt[o2][c2] = f2b(fw[o2 * 384 + c2]);
  }
  __syncthreads();
  gemm_acc();
  __syncthreads();

  // stage 3: y_att = y*ca_y  through final_w[:, 128:256]
  const float* cay = cab + b * 256 + 128;
  for (int o = t; o < 8192; o += 512) {
    int c = o >> 6, pos = o & 63;
    size_t g = (size_t)b * CHW_ + (size_t)c * HW_ + (y0 + (pos >> 3)) * W_ + x0 + (pos & 7);
    A[pos][c] = y[g] * cay[c];
  }
  for (int idx = t; idx < 16384; idx += 512) {
    int o2 = idx >> 7, c2 = idx & 127;
    Wt[o2][c2] = f2b(fw[o2 * 384 + 128 + c2]);
  }
  __syncthreads();
  gemm_acc();
  __syncthreads();

  // epilogue: bias + BN + ReLU -> LDS stage -> coalesced write
  #pragma unroll
  for (int j = 0; j < 4; ++j) {
    int och = og + 32 * j;
    float zb = bc[och];
    float inv = rsqrtf(bnv[och] + 1e-5f);
    float gsc = inv * bng[och];
    float mm = bnm[och], ab = bnb[och];
    #pragma unroll
    for (int i = 0; i < 4; ++i) {
      float z = acc[i][j] + zb;
      z = (z - mm) * gsc + ab;
      fst[pg * 4 + i][och] = fmaxf(z, 0.f);
    }
  }
  __syncthreads();
  for (int idx = t; idx < 8192; idx += 512) {
    int c = idx >> 6, pos = idx & 63;
    outp[(size_t)b * CHW_ + (size_t)c * HW_ + (y0 + (pos >> 3)) * W_ + x0 + (pos & 7)] =
        fst[pos][c];
  }
}

// ---------------- launcher ----------------
extern "C" void kernel_launch(void* const* d_in, const int* in_sizes, int n_in,
                              void* d_out, int out_size, void* d_ws, size_t ws_size,
                              hipStream_t stream) {
  const float* x       = (const float*)d_in[0];
  const float* y       = (const float*)d_in[1];
  const float* ca_w1   = (const float*)d_in[2];
  const float* ca_b1   = (const float*)d_in[3];
  const float* ca_w2   = (const float*)d_in[4];
  const float* ca_b2   = (const float*)d_in[5];
  const float* final_w = (const float*)d_in[6];
  const float* final_b = (const float*)d_in[7];
  const float* bn_g    = (const float*)d_in[8];
  const float* bn_b    = (const float*)d_in[9];
  const float* bn_m    = (const float*)d_in[10];
  const float* bn_v    = (const float*)d_in[11];
  const float* q_dw_w  = (const float*)d_in[12];
  const float* q_dw_b  = (const float*)d_in[13];
  const float* q_pw_w  = (const float*)d_in[14];
  const float* q_pw_b  = (const float*)d_in[15];
  const float* k_dw_w  = (const float*)d_in[16];
  const float* k_dw_b  = (const float*)d_in[17];
  const float* k_pw_w  = (const float*)d_in[18];
  const float* k_pw_b  = (const float*)d_in[19];
  const float* v_dw_w  = (const float*)d_in[20];
  const float* v_dw_b  = (const float*)d_in[21];
  const float* v_pw_w  = (const float*)d_in[22];
  const float* v_pw_b  = (const float*)d_in[23];
  const float* p_dw_w  = (const float*)d_in[24];
  const float* p_dw_b  = (const float*)d_in[25];
  const float* p_pw_w  = (const float*)d_in[26];
  const float* p_pw_b  = (const float*)d_in[27];

  char* ws = (char*)d_ws;
  float* sums = (float*)(ws + 0);              // 8 KB
  float* cab  = (float*)(ws + 8192);           // 8 KB
  float* Wc   = (float*)(ws + 16384);          // 64 KB
  float* bc   = (float*)(ws + 81920);          // 0.5 KB
  unsigned short* outb = (unsigned short*)(ws + (1 << 20));  // 33.5 MB bf16

  k_pool<<<2048, 256, 0, stream>>>(x, y, sums);
  k_ca<<<8, 256, 0, stream>>>(sums, ca_w1, ca_b1, ca_w2, ca_b2, cab);
  k_wc<<<128, 128, 0, stream>>>(final_w, final_b, p_pw_w, p_pw_b, Wc, bc);
  k_qkv_attn<<<2048, 512, 0, stream>>>(x, y, cab,
      q_dw_w, q_dw_b, q_pw_w, q_pw_b,
      k_dw_w, k_dw_b, k_pw_w, k_pw_b,
      v_dw_w, v_dw_b, v_pw_w, v_pw_b, outb);
  k_final<<<2048, 512, 0, stream>>>(x, y, cab, outb,
      p_dw_w, p_dw_b, Wc, bc, final_w,
      bn_g, bn_b, bn_m, bn_v, (float*)d_out);
}

// Round 2
// 541.397 us; speedup vs baseline: 3.6400x; 3.6400x over previous
//
#include <hip/hip_runtime.h>

typedef __attribute__((ext_vector_type(8))) short short8;
typedef __attribute__((ext_vector_type(4))) float f32x4;

static constexpr int C_ = 128, H_ = 128, W_ = 128;
static constexpr int HW_ = H_ * W_;
static constexpr int CHW_ = C_ * HW_;

__device__ __forceinline__ unsigned short f2b(float f) {
  union { float f; unsigned u; } cv; cv.f = f;
  unsigned r = cv.u + 0x7FFFu + ((cv.u >> 16) & 1u);
  return (unsigned short)(r >> 16);
}
__device__ __forceinline__ float b2f(unsigned short h) {
  union { unsigned u; float f; } cv; cv.u = ((unsigned)h) << 16;
  return cv.f;
}
// swizzled byte offset within a 64-row x 256B-row LDS tile
__device__ __forceinline__ int swzo(int pos, int byteInRow) {
  return pos * 256 + (byteInRow ^ ((pos & 7) << 4));
}

// ---------------- K1: per-(b, channel-of-concat) sums ----------------
__global__ __launch_bounds__(256) void k_pool(const float* __restrict__ x,
                                              const float* __restrict__ y,
                                              float* __restrict__ sums) {
  int blk = blockIdx.x;
  int b = blk >> 8, c = blk & 255;
  const float* src = (c < C_) ? (x + (size_t)b * CHW_ + (size_t)c * HW_)
                              : (y + (size_t)b * CHW_ + (size_t)(c - C_) * HW_);
  const float4* s4 = (const float4*)src;
  float acc = 0.f;
  for (int i = threadIdx.x; i < HW_ / 4; i += 256) {
    float4 v = s4[i];
    acc += v.x + v.y + v.z + v.w;
  }
  for (int off = 32; off; off >>= 1) acc += __shfl_down(acc, off, 64);
  __shared__ float red[4];
  int lane = threadIdx.x & 63, wv = threadIdx.x >> 6;
  if (lane == 0) red[wv] = acc;
  __syncthreads();
  if (threadIdx.x == 0) sums[blk] = red[0] + red[1] + red[2] + red[3];
}

// ---------------- K2: channel attention ----------------
__global__ __launch_bounds__(256) void k_ca(const float* __restrict__ sums,
                                            const float* __restrict__ w1,
                                            const float* __restrict__ b1,
                                            const float* __restrict__ w2,
                                            const float* __restrict__ b2,
                                            float* __restrict__ ca) {
  int b = blockIdx.x;
  __shared__ float pooled[256];
  __shared__ float hb[16];
  int t = threadIdx.x;
  pooled[t] = sums[b * 256 + t] * (1.f / 16384.f);
  __syncthreads();
  if (t < 16) {
    float s = b1[t];
    for (int j = 0; j < 256; ++j) s += w1[t * 256 + j] * pooled[j];
    hb[t] = fmaxf(s, 0.f);
  }
  __syncthreads();
  float s = b2[t];
  for (int r = 0; r < 16; ++r) s += w2[t * 16 + r] * hb[r];
  ca[b * 256 + t] = 1.f / (1.f + __expf(-s));
}

// ---------------- K3: weight prep (bf16 pack + Wc fold) ----------------
// grid 768 = 6 mats x 128 rows; Wb layout [mat][out][in] bf16.
// mats: 0=qpw 1=kpw 2=vpw 3=Wc(final_w3 . proj_pw) 4=fw1 5=fw2
__global__ __launch_bounds__(128) void k_prep(
    const float* __restrict__ qpw, const float* __restrict__ kpw,
    const float* __restrict__ vpw,
    const float* __restrict__ fw, const float* __restrict__ fb,
    const float* __restrict__ ppw, const float* __restrict__ ppb,
    unsigned short* __restrict__ Wb, float* __restrict__ bc) {
  int mat = blockIdx.x >> 7, o = blockIdx.x & 127, c = threadIdx.x;
  float v;
  if (mat == 0) v = qpw[o * 128 + c];
  else if (mat == 1) v = kpw[o * 128 + c];
  else if (mat == 2) v = vpw[o * 128 + c];
  else if (mat == 3) {
    float a = 0.f;
    for (int m = 0; m < 128; ++m) a += fw[o * 384 + 256 + m] * ppw[m * 128 + c];
    v = a;
    if (c == 0) {
      float bb = fb[o];
      for (int m = 0; m < 128; ++m) bb += fw[o * 384 + 256 + m] * ppb[m];
      bc[o] = bb;
    }
  } else if (mat == 4) v = fw[o * 384 + c];
  else v = fw[o * 384 + 128 + c];
  Wb[((size_t)mat << 14) + o * 128 + c] = f2b(v);
}

// ---------------- K4: fused dw + MFMA pw q/k/v + window attention ----------------
__global__ __launch_bounds__(512, 4) void k_qkv_attn(
    const float* __restrict__ x, const float* __restrict__ y,
    const float* __restrict__ cab,
    const float* __restrict__ qdw, const float* __restrict__ qdb,
    const float* __restrict__ kdw, const float* __restrict__ kdb,
    const float* __restrict__ vdw, const float* __restrict__ vdb,
    const unsigned short* __restrict__ Wqkv,
    const float* __restrict__ qpb, const float* __restrict__ kpb,
    const float* __restrict__ vpb,
    unsigned short* __restrict__ outb) {
  __shared__ __align__(16) char lds[81920];
  constexpr int QS = 0, KS = 16384, VS = 32768, A1 = 49152, A2 = 65536;
  constexpr int HA = 16384, OS = 49152;  // halo over ks/vs; out-stage over A1

  const int t = threadIdx.x;
  const int l = t & 63;
  const int w = t >> 6;
  const int blk = blockIdx.x;
  const int b = blk >> 8, tr = blk & 255;
  const int y0 = (tr >> 4) << 3, x0 = (tr & 15) << 3;

  unsigned short* hal = (unsigned short*)(lds + HA);  // [128][102] pitch-102

  auto load_halo = [&](const float* src) {
    for (int idx = t; idx < 12800; idx += 512) {
      int c = idx / 100;
      int r = idx - c * 100;
      int hy = r / 10, hx = r - hy * 10;
      int gy = y0 - 1 + hy, gx = x0 - 1 + hx;
      float v = 0.f;
      if ((unsigned)gy < 128u && (unsigned)gx < 128u)
        v = src[(size_t)c * HW_ + gy * W_ + gx];
      hal[c * 102 + r] = f2b(v);
    }
  };
  auto dw_into = [&](const float* wdw, const float* bdw, const float* cas,
                     int aOff) {
    for (int o = t; o < 8192; o += 512) {
      int c = o & 127, pos = o >> 7;
      int py = pos >> 3, px = pos & 7;
      const float* wp = wdw + c * 9;
      const unsigned short* h0 = hal + c * 102 + py * 10 + px;
      float s = b2f(h0[0]) * wp[0] + b2f(h0[1]) * wp[1] + b2f(h0[2]) * wp[2]
              + b2f(h0[10]) * wp[3] + b2f(h0[11]) * wp[4] + b2f(h0[12]) * wp[5]
              + b2f(h0[20]) * wp[6] + b2f(h0[21]) * wp[7] + b2f(h0[22]) * wp[8];
      float rv = s * cas[c] + bdw[c];
      *(unsigned short*)(lds + aOff + swzo(pos, 2 * c)) = f2b(rv);
    }
  };

  const int mtile = w & 3, nbase = (w >> 2) * 64;

  auto gemm_store = [&](int aOff, const unsigned short* Wm, const float* bias,
                        int dstOff) {
    f32x4 acc[4];
    #pragma unroll
    for (int nt = 0; nt < 4; ++nt) acc[nt] = f32x4{0.f, 0.f, 0.f, 0.f};
    #pragma unroll
    for (int ks = 0; ks < 4; ++ks) {
      short8 a = *(const short8*)(lds + aOff +
                   swzo(mtile * 16 + (l & 15), ks * 64 + (l >> 4) * 16));
      #pragma unroll
      for (int nt = 0; nt < 4; ++nt) {
        int n = nbase + nt * 16 + (l & 15);
        short8 bf = *(const short8*)(Wm + n * 128 + ks * 32 + (l >> 4) * 8);
        acc[nt] = __builtin_amdgcn_mfma_f32_16x16x32_bf16(a, bf, acc[nt], 0, 0, 0);
      }
    }
    #pragma unroll
    for (int nt = 0; nt < 4; ++nt) {
      int ch = nbase + nt * 16 + (l & 15);
      float bv = bias[ch];
      #pragma unroll
      for (int r2 = 0; r2 < 4; ++r2) {
        int pos = mtile * 16 + (l >> 4) * 4 + r2;
        *(unsigned short*)(lds + dstOff + swzo(pos, 2 * ch)) = f2b(acc[nt][r2] + bv);
      }
    }
  };

  const float* cax = cab + b * 256;
  const float* cay = cax + 128;

  load_halo(y + (size_t)b * CHW_);
  __syncthreads();
  dw_into(qdw, qdb, cay, A1);
  __syncthreads();
  gemm_store(A1, Wqkv, qpb, QS);
  load_halo(x + (size_t)b * CHW_);
  __syncthreads();
  dw_into(kdw, kdb, cax, A1);
  dw_into(vdw, vdb, cax, A2);
  __syncthreads();
  gemm_store(A1, Wqkv + 16384, kpb, KS);
  gemm_store(A2, Wqkv + 32768, vpb, VS);
  __syncthreads();

  // ---- window attention: 4 windows x 8 heads x 16 q-rows = 512 tasks
  {
    int wi = t >> 7, h8 = (t >> 4) & 7, n = t & 15;
    int wy = (wi >> 1) << 2, wx = (wi & 1) << 2;
    int qpos = (wy + (n >> 2)) * 8 + wx + (n & 3);
    int co2 = 32 * h8;
    int swq = (qpos & 7) << 4;
    float qv[16];
    short8 qa = *(const short8*)(lds + QS + qpos * 256 + (co2 ^ swq));
    short8 qb2 = *(const short8*)(lds + QS + qpos * 256 + ((co2 + 16) ^ swq));
    #pragma unroll
    for (int d = 0; d < 8; ++d) {
      qv[d] = b2f((unsigned short)qa[d]);
      qv[8 + d] = b2f((unsigned short)qb2[d]);
    }
    float sc[16];
    float m = -1e30f;
    #pragma unroll
    for (int jj = 0; jj < 16; ++jj) {
      int kpos = (wy + (jj >> 2)) * 8 + wx + (jj & 3);
      int swk = (kpos & 7) << 4;
      short8 ka = *(const short8*)(lds + KS + kpos * 256 + (co2 ^ swk));
      short8 kb = *(const short8*)(lds + KS + kpos * 256 + ((co2 + 16) ^ swk));
      float s = 0.f;
      #pragma unroll
      for (int d = 0; d < 8; ++d) s = fmaf(qv[d], b2f((unsigned short)ka[d]), s);
      #pragma unroll
      for (int d = 0; d < 8; ++d) s = fmaf(qv[8 + d], b2f((unsigned short)kb[d]), s);
      s *= 0.25f;
      sc[jj] = s;
      m = fmaxf(m, s);
    }
    float lsum = 0.f;
    #pragma unroll
    for (int jj = 0; jj < 16; ++jj) { float e = __expf(sc[jj] - m); sc[jj] = e; lsum += e; }
    float rl = 1.f / lsum;
    float ov[16];
    #pragma unroll
    for (int d = 0; d < 16; ++d) ov[d] = 0.f;
    #pragma unroll
    for (int jj = 0; jj < 16; ++jj) {
      int vpos = (wy + (jj >> 2)) * 8 + wx + (jj & 3);
      int swv = (vpos & 7) << 4;
      short8 va = *(const short8*)(lds + VS + vpos * 256 + (co2 ^ swv));
      short8 vb = *(const short8*)(lds + VS + vpos * 256 + ((co2 + 16) ^ swv));
      float p = sc[jj] * rl;
      #pragma unroll
      for (int d = 0; d < 8; ++d) ov[d] = fmaf(p, b2f((unsigned short)va[d]), ov[d]);
      #pragma unroll
      for (int d = 0; d < 8; ++d) ov[8 + d] = fmaf(p, b2f((unsigned short)vb[d]), ov[8 + d]);
    }
    short8 oa, ob;
    #pragma unroll
    for (int d = 0; d < 8; ++d) {
      oa[d] = (short)f2b(ov[d]);
      ob[d] = (short)f2b(ov[8 + d]);
    }
    *(short8*)(lds + OS + qpos * 256 + (co2 ^ swq)) = oa;
    *(short8*)(lds + OS + qpos * 256 + ((co2 + 16) ^ swq)) = ob;
  }
  __syncthreads();
  {
    unsigned short* dst = outb + (size_t)b * CHW_;
    for (int idx = t; idx < 8192; idx += 512) {
      int c = idx >> 6, pos = idx & 63;
      dst[(size_t)c * HW_ + (y0 + (pos >> 3)) * W_ + x0 + (pos & 7)] =
          *(const unsigned short*)(lds + OS + swzo(pos, 2 * c));
    }
  }
}

// ---------------- K5: proj-dw + 3 accumulated MFMA GEMMs + BN + ReLU ----------------
__global__ __launch_bounds__(512, 4) void k_final(
    const float* __restrict__ x, const float* __restrict__ y,
    const float* __restrict__ cab,
    const unsigned short* __restrict__ outb,
    const float* __restrict__ pdw, const float* __restrict__ pdb,
    const unsigned short* __restrict__ W3,
    const float* __restrict__ bc,
    const float* __restrict__ bng, const float* __restrict__ bnb,
    const float* __restrict__ bnm, const float* __restrict__ bnv,
    float* __restrict__ outp) {
  __shared__ __align__(16) char lds[49408];
  constexpr int A1 = 0, HA = 16384, OS = 16384;  // OS (f32 [64][129]) over halo

  const int t = threadIdx.x, l = t & 63, w = t >> 6;
  const int blk = blockIdx.x, b = blk >> 8, tr = blk & 255;
  const int y0 = (tr >> 4) << 3, x0 = (tr & 15) << 3;
  unsigned short* hal = (unsigned short*)(lds + HA);
  const int mtile = w & 3, nbase = (w >> 2) * 64;

  f32x4 acc[4];
  #pragma unroll
  for (int nt = 0; nt < 4; ++nt) acc[nt] = f32x4{0.f, 0.f, 0.f, 0.f};

  auto gemm_acc = [&](const unsigned short* Wm) {
    #pragma unroll
    for (int ks = 0; ks < 4; ++ks) {
      short8 a = *(const short8*)(lds + A1 +
                   swzo(mtile * 16 + (l & 15), ks * 64 + (l >> 4) * 16));
      #pragma unroll
      for (int nt = 0; nt < 4; ++nt) {
        int n = nbase + nt * 16 + (l & 15);
        short8 bf = *(const short8*)(Wm + n * 128 + ks * 32 + (l >> 4) * 8);
        acc[nt] = __builtin_amdgcn_mfma_f32_16x16x32_bf16(a, bf, acc[nt], 0, 0, 0);
      }
    }
  };

  // proj-dw input halo (bf16 from ws)
  {
    const unsigned short* src = outb + (size_t)b * CHW_;
    for (int idx = t; idx < 12800; idx += 512) {
      int c = idx / 100, r = idx - c * 100;
      int hy = r / 10, hx = r - hy * 10;
      int gy = y0 - 1 + hy, gx = x0 - 1 + hx;
      unsigned short v = 0;
      if ((unsigned)gy < 128u && (unsigned)gx < 128u)
        v = src[(size_t)c * HW_ + gy * W_ + gx];
      hal[c * 102 + r] = v;
    }
  }
  __syncthreads();
  for (int o = t; o < 8192; o += 512) {
    int c = o & 127, pos = o >> 7;
    int py = pos >> 3, px = pos & 7;
    const float* wp = pdw + c * 9;
    const unsigned short* h0 = hal + c * 102 + py * 10 + px;
    float s = b2f(h0[0]) * wp[0] + b2f(h0[1]) * wp[1] + b2f(h0[2]) * wp[2]
            + b2f(h0[10]) * wp[3] + b2f(h0[11]) * wp[4] + b2f(h0[12]) * wp[5]
            + b2f(h0[20]) * wp[6] + b2f(h0[21]) * wp[7] + b2f(h0[22]) * wp[8];
    *(unsigned short*)(lds + A1 + swzo(pos, 2 * c)) = f2b(s + pdb[c]);
  }
  __syncthreads();
  gemm_acc(W3);  // folded Wc
  __syncthreads();
  for (int o = t; o < 8192; o += 512) {
    int c = o >> 6, pos = o & 63;
    size_t g = (size_t)b * CHW_ + (size_t)c * HW_ + (y0 + (pos >> 3)) * W_ + x0 + (pos & 7);
    *(unsigned short*)(lds + A1 + swzo(pos, 2 * c)) = f2b(x[g] * y[g]);
  }
  __syncthreads();
  gemm_acc(W3 + 16384);  // fw1
  __syncthreads();
  const float* cay = cab + b * 256 + 128;
  for (int o = t; o < 8192; o += 512) {
    int c = o >> 6, pos = o & 63;
    size_t g = (size_t)b * CHW_ + (size_t)c * HW_ + (y0 + (pos >> 3)) * W_ + x0 + (pos & 7);
    *(unsigned short*)(lds + A1 + swzo(pos, 2 * c)) = f2b(y[g] * cay[c]);
  }
  __syncthreads();
  gemm_acc(W3 + 32768);  // fw2

  float* fst = (float*)(lds + OS);  // [64][129]
  #pragma unroll
  for (int nt = 0; nt < 4; ++nt) {
    int ch = nbase + nt * 16 + (l & 15);
    float zb = bc[ch];
    float inv = rsqrtf(bnv[ch] + 1e-5f);
    float gsc = inv * bng[ch];
    float mm = bnm[ch], ab = bnb[ch];
    #pragma unroll
    for (int r2 = 0; r2 < 4; ++r2) {
      int pos = mtile * 16 + (l >> 4) * 4 + r2;
      float z = acc[nt][r2] + zb;
      z = (z - mm) * gsc + ab;
      fst[pos * 129 + ch] = fmaxf(z, 0.f);
    }
  }
  __syncthreads();
  for (int idx = t; idx < 8192; idx += 512) {
    int c = idx >> 6, pos = idx & 63;
    outp[(size_t)b * CHW_ + (size_t)c * HW_ + (y0 + (pos >> 3)) * W_ + x0 + (pos & 7)] =
        fst[pos * 129 + c];
  }
}

// ---------------- launcher ----------------
extern "C" void kernel_launch(void* const* d_in, const int* in_sizes, int n_in,
                              void* d_out, int out_size, void* d_ws, size_t ws_size,
                              hipStream_t stream) {
  const float* x       = (const float*)d_in[0];
  const float* y       = (const float*)d_in[1];
  const float* ca_w1   = (const float*)d_in[2];
  const float* ca_b1   = (const float*)d_in[3];
  const float* ca_w2   = (const float*)d_in[4];
  const float* ca_b2   = (const float*)d_in[5];
  const float* final_w = (const float*)d_in[6];
  const float* final_b = (const float*)d_in[7];
  const float* bn_g    = (const float*)d_in[8];
  const float* bn_b    = (const float*)d_in[9];
  const float* bn_m    = (const float*)d_in[10];
  const float* bn_v    = (const float*)d_in[11];
  const float* q_dw_w  = (const float*)d_in[12];
  const float* q_dw_b  = (const float*)d_in[13];
  const float* q_pw_w  = (const float*)d_in[14];
  const float* q_pw_b  = (const float*)d_in[15];
  const float* k_dw_w  = (const float*)d_in[16];
  const float* k_dw_b  = (const float*)d_in[17];
  const float* k_pw_w  = (const float*)d_in[18];
  const float* k_pw_b  = (const float*)d_in[19];
  const float* v_dw_w  = (const float*)d_in[20];
  const float* v_dw_b  = (const float*)d_in[21];
  const float* v_pw_w  = (const float*)d_in[22];
  const float* v_pw_b  = (const float*)d_in[23];
  const float* p_dw_w  = (const float*)d_in[24];
  const float* p_dw_b  = (const float*)d_in[25];
  const float* p_pw_w  = (const float*)d_in[26];
  const float* p_pw_b  = (const float*)d_in[27];

  char* ws = (char*)d_ws;
  float* sums = (float*)(ws + 0);                       // 8 KB
  float* cab  = (float*)(ws + 8192);                    // 8 KB
  unsigned short* Wqkv = (unsigned short*)(ws + 16384); // 3 x 32 KB
  unsigned short* W3   = Wqkv + 3 * 16384;              // 3 x 32 KB
  float* bc   = (float*)(ws + 212992);                  // 512 B
  unsigned short* outb = (unsigned short*)(ws + (1 << 20));  // 33.5 MB bf16

  k_pool<<<2048, 256, 0, stream>>>(x, y, sums);
  k_ca<<<8, 256, 0, stream>>>(sums, ca_w1, ca_b1, ca_w2, ca_b2, cab);
  k_prep<<<768, 128, 0, stream>>>(q_pw_w, k_pw_w, v_pw_w, final_w, final_b,
                                  p_pw_w, p_pw_b, Wqkv, bc);
  k_qkv_attn<<<2048, 512, 0, stream>>>(x, y, cab,
      q_dw_w, q_dw_b, k_dw_w, k_dw_b, v_dw_w, v_dw_b,
      Wqkv, q_pw_b, k_pw_b, v_pw_b, outb);
  k_final<<<2048, 512, 0, stream>>>(x, y, cab, outb,
      p_dw_w, p_dw_b, W3, bc,
      bn_g, bn_b, bn_m, bn_v, (float*)d_out);
}

// Round 3
// 448.842 us; speedup vs baseline: 4.3906x; 1.2062x over previous
//
#include <hip/hip_runtime.h>

typedef __attribute__((ext_vector_type(8))) short short8;
typedef __attribute__((ext_vector_type(4))) float f32x4;
typedef __attribute__((ext_vector_type(2))) unsigned u32x2;
typedef __attribute__((ext_vector_type(4))) unsigned u32x4;

static constexpr int C_ = 128, H_ = 128, W_ = 128;
static constexpr int HW_ = H_ * W_;
static constexpr int CHW_ = C_ * HW_;

__device__ __forceinline__ unsigned short f2b(float f) {
  union { float f; unsigned u; } cv; cv.f = f;
  unsigned r = cv.u + 0x7FFFu + ((cv.u >> 16) & 1u);
  return (unsigned short)(r >> 16);
}
__device__ __forceinline__ float b2f(unsigned short h) {
  union { unsigned u; float f; } cv; cv.u = ((unsigned)h) << 16;
  return cv.f;
}
__device__ __forceinline__ float uasf(unsigned u) {
  union { unsigned u; float f; } cv; cv.u = u; return cv.f;
}
// swizzled byte offset within a 64-row x 256B-row LDS tile
__device__ __forceinline__ int swzo(int pos, int byteInRow) {
  return pos * 256 + (byteInRow ^ ((pos & 7) << 4));
}

// ---------------- K1: per-(b, channel-of-concat) sums ----------------
__global__ __launch_bounds__(256) void k_pool(const float* __restrict__ x,
                                              const float* __restrict__ y,
                                              float* __restrict__ sums) {
  int blk = blockIdx.x;
  int b = blk >> 8, c = blk & 255;
  const float* src = (c < C_) ? (x + (size_t)b * CHW_ + (size_t)c * HW_)
                              : (y + (size_t)b * CHW_ + (size_t)(c - C_) * HW_);
  const float4* s4 = (const float4*)src;
  float acc = 0.f;
  for (int i = threadIdx.x; i < HW_ / 4; i += 256) {
    float4 v = s4[i];
    acc += v.x + v.y + v.z + v.w;
  }
  for (int off = 32; off; off >>= 1) acc += __shfl_down(acc, off, 64);
  __shared__ float red[4];
  int lane = threadIdx.x & 63, wv = threadIdx.x >> 6;
  if (lane == 0) red[wv] = acc;
  __syncthreads();
  if (threadIdx.x == 0) sums[blk] = red[0] + red[1] + red[2] + red[3];
}

// ---------------- K2: channel attention ----------------
__global__ __launch_bounds__(256) void k_ca(const float* __restrict__ sums,
                                            const float* __restrict__ w1,
                                            const float* __restrict__ b1,
                                            const float* __restrict__ w2,
                                            const float* __restrict__ b2,
                                            float* __restrict__ ca) {
  int b = blockIdx.x;
  __shared__ float pooled[256];
  __shared__ float hb[16];
  int t = threadIdx.x;
  pooled[t] = sums[b * 256 + t] * (1.f / 16384.f);
  __syncthreads();
  if (t < 16) {
    float s = b1[t];
    for (int j = 0; j < 256; ++j) s += w1[t * 256 + j] * pooled[j];
    hb[t] = fmaxf(s, 0.f);
  }
  __syncthreads();
  float s = b2[t];
  for (int r = 0; r < 16; ++r) s += w2[t * 16 + r] * hb[r];
  ca[b * 256 + t] = 1.f / (1.f + __expf(-s));
}

// ---------------- K3: weight prep ----------------
// blocks 0..767: mats 0=qpw 1=kpw 2=vpw 3=Wc 4=fw1 (5 unused-slot skipped)
// blocks 768..1791: W2b[b][o][c] = fw2[o][c] * ca_y[b][c]
__global__ __launch_bounds__(128) void k_prep(
    const float* __restrict__ qpw, const float* __restrict__ kpw,
    const float* __restrict__ vpw,
    const float* __restrict__ fw, const float* __restrict__ fb,
    const float* __restrict__ ppw, const float* __restrict__ ppb,
    const float* __restrict__ cab,
    unsigned short* __restrict__ Wb, unsigned short* __restrict__ W2b,
    float* __restrict__ bc) {
  int blk = blockIdx.x, c = threadIdx.x;
  if (blk < 768) {
    int mat = blk >> 7, o = blk & 127;
    float v = 0.f;
    if (mat == 0) v = qpw[o * 128 + c];
    else if (mat == 1) v = kpw[o * 128 + c];
    else if (mat == 2) v = vpw[o * 128 + c];
    else if (mat == 3) {
      float a = 0.f;
      for (int m = 0; m < 128; ++m) a += fw[o * 384 + 256 + m] * ppw[m * 128 + c];
      v = a;
      if (c == 0) {
        float bb = fb[o];
        for (int m = 0; m < 128; ++m) bb += fw[o * 384 + 256 + m] * ppb[m];
        bc[o] = bb;
      }
    } else if (mat == 4) v = fw[o * 384 + c];
    else v = 0.f;
    Wb[((size_t)mat << 14) + o * 128 + c] = f2b(v);
  } else {
    int bb = (blk - 768) >> 7, o = blk & 127;
    W2b[((size_t)bb << 14) + o * 128 + c] =
        f2b(fw[o * 384 + 128 + c] * cab[bb * 256 + 128 + c]);
  }
}

// ---------------- K4: fused dw + MFMA pw q/k/v + MFMA window attention ------
// LDS map (80K): QS[0,16K) KS[16K,32K) VT[32K,48K) A1[48K,64K) A2[64K,80K)
// halo aliases [16K,42.5K) (over KS/VT before they're written);
// scratch aliases A1; OS aliases A2.
__global__ __launch_bounds__(512, 4) void k_qkv_attn(
    const float* __restrict__ x, const float* __restrict__ y,
    const float* __restrict__ cab,
    const float* __restrict__ qdw, const float* __restrict__ qdb,
    const float* __restrict__ kdw, const float* __restrict__ kdb,
    const float* __restrict__ vdw, const float* __restrict__ vdb,
    const unsigned short* __restrict__ Wqkv,
    const float* __restrict__ qpb, const float* __restrict__ kpb,
    const float* __restrict__ vpb,
    unsigned short* __restrict__ outb) {
  __shared__ __align__(16) char lds[81920];
  constexpr int QS = 0, KS = 16384, VT = 32768, A1 = 49152, A2 = 65536;
  constexpr int HA = 16384, SCR = 49152, OS = 65536;

  const int t = threadIdx.x;
  const int l = t & 63;
  const int w = t >> 6;
  const int lm = l & 15, g = l >> 4;
  const int bs = ((blockIdx.x & 7) << 8) | (blockIdx.x >> 3);  // XCD-chunked
  const int b = bs >> 8, tr = bs & 255;
  const int y0 = (tr >> 4) << 3, x0 = (tr & 15) << 3;

  unsigned short* hal = (unsigned short*)(lds + HA);  // [128][102]

  auto load_halo = [&](const float* src) {
    for (int idx = t; idx < 12800; idx += 512) {
      int c = idx / 100;
      int r = idx - c * 100;
      int hy = r / 10, hx = r - hy * 10;
      int gy = y0 - 1 + hy, gx = x0 - 1 + hx;
      float v = 0.f;
      if ((unsigned)gy < 128u && (unsigned)gx < 128u)
        v = src[(size_t)c * HW_ + gy * W_ + gx];
      hal[c * 102 + r] = f2b(v);
    }
  };

  // strip-mined dw: thread handles (c, py) rows of 8 outputs; 2 tasks each.
  auto dw_q = [&](const float* wdw, const float* bdw, const float* cas) {
    #pragma unroll
    for (int it = 0; it < 2; ++it) {
      int u = t + it * 512;
      int c = u & 127, py = u >> 7;
      const float* wp = wdw + c * 9;
      float w0 = wp[0], w1 = wp[1], w2 = wp[2], w3 = wp[3], w4 = wp[4],
            w5 = wp[5], w6 = wp[6], w7 = wp[7], w8 = wp[8];
      float cam = cas[c], bb = bdw[c];
      float rv[3][10];
      #pragma unroll
      for (int rr = 0; rr < 3; ++rr) {
        const unsigned* rp = (const unsigned*)(hal + c * 102 + (py + rr) * 10);
        #pragma unroll
        for (int e = 0; e < 5; ++e) {
          unsigned pk = rp[e];
          rv[rr][2 * e] = uasf(pk << 16);
          rv[rr][2 * e + 1] = uasf(pk & 0xffff0000u);
        }
      }
      #pragma unroll
      for (int px = 0; px < 8; ++px) {
        float s = rv[0][px] * w0 + rv[0][px + 1] * w1 + rv[0][px + 2] * w2
                + rv[1][px] * w3 + rv[1][px + 1] * w4 + rv[1][px + 2] * w5
                + rv[2][px] * w6 + rv[2][px + 1] * w7 + rv[2][px + 2] * w8;
        *(unsigned short*)(lds + A1 + swzo(py * 8 + px, 2 * c)) =
            f2b(s * cam + bb);
      }
    }
  };
  // combined k+v dw sharing row loads
  auto dw_kv = [&](const float* kw, const float* kb2, const float* vw,
                   const float* vb2, const float* cas) {
    #pragma unroll
    for (int it = 0; it < 2; ++it) {
      int u = t + it * 512;
      int c = u & 127, py = u >> 7;
      const float* kp = kw + c * 9;
      const float* vp = vw + c * 9;
      float cam = cas[c], kbb = kb2[c], vbb = vb2[c];
      float rv[3][10];
      #pragma unroll
      for (int rr = 0; rr < 3; ++rr) {
        const unsigned* rp = (const unsigned*)(hal + c * 102 + (py + rr) * 10);
        #pragma unroll
        for (int e = 0; e < 5; ++e) {
          unsigned pk = rp[e];
          rv[rr][2 * e] = uasf(pk << 16);
          rv[rr][2 * e + 1] = uasf(pk & 0xffff0000u);
        }
      }
      #pragma unroll
      for (int px = 0; px < 8; ++px) {
        float sk = rv[0][px] * kp[0] + rv[0][px + 1] * kp[1] + rv[0][px + 2] * kp[2]
                 + rv[1][px] * kp[3] + rv[1][px + 1] * kp[4] + rv[1][px + 2] * kp[5]
                 + rv[2][px] * kp[6] + rv[2][px + 1] * kp[7] + rv[2][px + 2] * kp[8];
        float sv = rv[0][px] * vp[0] + rv[0][px + 1] * vp[1] + rv[0][px + 2] * vp[2]
                 + rv[1][px] * vp[3] + rv[1][px + 1] * vp[4] + rv[1][px + 2] * vp[5]
                 + rv[2][px] * vp[6] + rv[2][px + 1] * vp[7] + rv[2][px + 2] * vp[8];
        int so = swzo(py * 8 + px, 2 * c);
        *(unsigned short*)(lds + A1 + so) = f2b(sk * cam + kbb);
        *(unsigned short*)(lds + A2 + so) = f2b(sv * cam + vbb);
      }
    }
  };

  const int mtile = w & 3, nbase = (w >> 2) * 64;

  auto gemm_qk = [&](int aOff, const unsigned short* Wm, const float* bias,
                     int dstOff) {
    f32x4 acc[4];
    #pragma unroll
    for (int nt = 0; nt < 4; ++nt) acc[nt] = f32x4{0.f, 0.f, 0.f, 0.f};
    #pragma unroll
    for (int ks = 0; ks < 4; ++ks) {
      short8 a = *(const short8*)(lds + aOff +
                   swzo(mtile * 16 + lm, ks * 64 + g * 16));
      #pragma unroll
      for (int nt = 0; nt < 4; ++nt) {
        int n = nbase + nt * 16 + lm;
        short8 bf = *(const short8*)(Wm + n * 128 + ks * 32 + g * 8);
        acc[nt] = __builtin_amdgcn_mfma_f32_16x16x32_bf16(a, bf, acc[nt], 0, 0, 0);
      }
    }
    #pragma unroll
    for (int nt = 0; nt < 4; ++nt) {
      int ch = nbase + nt * 16 + lm;
      float bv = bias[ch];
      #pragma unroll
      for (int r2 = 0; r2 < 4; ++r2) {
        int pos = mtile * 16 + g * 4 + r2;
        *(unsigned short*)(lds + dstOff + swzo(pos, 2 * ch)) =
            f2b(acc[nt][r2] + bv);
      }
    }
  };
  // V gemm writing transposed window-major tile VT[ch][wcol^((ch&7)<<3)]
  auto gemm_v = [&](int aOff, const unsigned short* Wm, const float* bias) {
    f32x4 acc[4];
    #pragma unroll
    for (int nt = 0; nt < 4; ++nt) acc[nt] = f32x4{0.f, 0.f, 0.f, 0.f};
    #pragma unroll
    for (int ks = 0; ks < 4; ++ks) {
      short8 a = *(const short8*)(lds + aOff +
                   swzo(mtile * 16 + lm, ks * 64 + g * 16));
      #pragma unroll
      for (int nt = 0; nt < 4; ++nt) {
        int n = nbase + nt * 16 + lm;
        short8 bf = *(const short8*)(Wm + n * 128 + ks * 32 + g * 8);
        acc[nt] = __builtin_amdgcn_mfma_f32_16x16x32_bf16(a, bf, acc[nt], 0, 0, 0);
      }
    }
    int py0 = mtile * 2 + (g >> 1);
    int wwin = ((py0 >> 2) << 1) | (g & 1);
    int kp0 = (py0 & 3) * 4;
    #pragma unroll
    for (int nt = 0; nt < 4; ++nt) {
      int ch = nbase + nt * 16 + lm;
      float bv = bias[ch];
      int col = (wwin * 16 + kp0) ^ ((ch & 7) << 3);
      unsigned lo = (unsigned)f2b(acc[nt][0] + bv) |
                    ((unsigned)f2b(acc[nt][1] + bv) << 16);
      unsigned hi = (unsigned)f2b(acc[nt][2] + bv) |
                    ((unsigned)f2b(acc[nt][3] + bv) << 16);
      *(u32x2*)(lds + VT + ch * 128 + 2 * col) = u32x2{lo, hi};
    }
  };

  const float* cax = cab + b * 256;
  const float* cay = cax + 128;

  load_halo(y + (size_t)b * CHW_);
  __syncthreads();
  dw_q(qdw, qdb, cay);
  __syncthreads();
  gemm_qk(A1, Wqkv, qpb, QS);
  load_halo(x + (size_t)b * CHW_);
  __syncthreads();
  dw_kv(kdw, kdb, vdw, vdb, cax);
  __syncthreads();
  gemm_qk(A1, Wqkv + 16384, kpb, KS);
  gemm_v(A2, Wqkv + 32768, vpb);
  __syncthreads();

  // ---- MFMA window attention: wave = head, 4 windows sequential ----
  {
    const int h = w;
    const int chb = h * 32;  // byte col base in QS/KS rows
    char* scr = lds + SCR + w * 512;
    const short8 zz = {};
    #pragma unroll
    for (int wi = 0; wi < 4; ++wi) {
      int wy = (wi >> 1) * 4, wx = (wi & 1) * 4;
      int rowp = (wy + (lm >> 2)) * 8 + wx + (lm & 3);  // wpos(wi, lm)
      short8 av = zz, bv = zz;
      if (g < 2) {
        av = *(const short8*)(lds + KS + swzo(rowp, chb + g * 16));
        bv = *(const short8*)(lds + QS + swzo(rowp, chb + g * 16));
      }
      f32x4 st = __builtin_amdgcn_mfma_f32_16x16x32_bf16(
          av, bv, f32x4{0.f, 0.f, 0.f, 0.f}, 0, 0, 0);
      // st[r] = S^T[kp=g*4+r][q=lm]
      float s0 = st[0] * 0.25f, s1 = st[1] * 0.25f,
            s2 = st[2] * 0.25f, s3 = st[3] * 0.25f;
      float mx = fmaxf(fmaxf(s0, s1), fmaxf(s2, s3));
      mx = fmaxf(mx, __shfl_xor(mx, 16, 64));
      mx = fmaxf(mx, __shfl_xor(mx, 32, 64));
      float e0 = __expf(s0 - mx), e1 = __expf(s1 - mx),
            e2 = __expf(s2 - mx), e3 = __expf(s3 - mx);
      float sm = e0 + e1 + e2 + e3;
      sm += __shfl_xor(sm, 16, 64);
      sm += __shfl_xor(sm, 32, 64);
      float rl = 1.f / sm;
      // P[q=lm][kp=g*4+0..3] -> scratch row lm
      unsigned p0 = (unsigned)f2b(e0 * rl) | ((unsigned)f2b(e1 * rl) << 16);
      unsigned p1 = (unsigned)f2b(e2 * rl) | ((unsigned)f2b(e3 * rl) << 16);
      *(u32x2*)(scr + lm * 32 + g * 8) = u32x2{p0, p1};
      short8 pb2 = zz, va = zz;
      if (g < 2) {
        pb2 = *(const short8*)(scr + lm * 32 + g * 16);
        int ch = h * 16 + lm;
        va = *(const short8*)(lds + VT + ch * 128 +
                              2 * ((wi * 16 + g * 8) ^ ((ch & 7) << 3)));
      }
      f32x4 ot = __builtin_amdgcn_mfma_f32_16x16x32_bf16(
          va, pb2, f32x4{0.f, 0.f, 0.f, 0.f}, 0, 0, 0);
      // ot[r] = out[q=lm][h*16 + g*4 + r]
      unsigned o0 = (unsigned)f2b(ot[0]) | ((unsigned)f2b(ot[1]) << 16);
      unsigned o1 = (unsigned)f2b(ot[2]) | ((unsigned)f2b(ot[3]) << 16);
      *(u32x2*)(lds + OS + swzo(rowp, chb + g * 8)) = u32x2{o0, o1};
    }
  }
  __syncthreads();
  {
    unsigned short* dst = outb + (size_t)b * CHW_;
    #pragma unroll
    for (int it = 0; it < 2; ++it) {
      int u = t + it * 512;
      int c = u & 127, py = u >> 7;
      unsigned v[4];
      #pragma unroll
      for (int p2 = 0; p2 < 4; ++p2) {
        unsigned lo = *(const unsigned short*)(lds + OS + swzo(py * 8 + p2 * 2, 2 * c));
        unsigned hi = *(const unsigned short*)(lds + OS + swzo(py * 8 + p2 * 2 + 1, 2 * c));
        v[p2] = lo | (hi << 16);
      }
      *(u32x4*)(dst + (size_t)c * HW_ + (y0 + py) * W_ + x0) =
          u32x4{v[0], v[1], v[2], v[3]};
    }
  }
}

// ---------------- K5: proj-dw + 3 accumulated MFMA GEMMs + BN + ReLU --------
// LDS: A[0,16K), halo/fst alias [16K, 49.7K)
__global__ __launch_bounds__(512, 6) void k_final(
    const float* __restrict__ x, const float* __restrict__ y,
    const unsigned short* __restrict__ outb,
    const float* __restrict__ pdw, const float* __restrict__ pdb,
    const unsigned short* __restrict__ W3,
    const unsigned short* __restrict__ W2b,
    const float* __restrict__ bc,
    const float* __restrict__ bng, const float* __restrict__ bnb,
    const float* __restrict__ bnm, const float* __restrict__ bnv,
    float* __restrict__ outp) {
  __shared__ __align__(16) char lds[49664];
  constexpr int A1 = 0, HA = 16384;

  const int t = threadIdx.x, l = t & 63, w = t >> 6;
  const int lm = l & 15, g = l >> 4;
  const int bs = ((blockIdx.x & 7) << 8) | (blockIdx.x >> 3);
  const int b = bs >> 8, tr = bs & 255;
  const int y0 = (tr >> 4) << 3, x0 = (tr & 15) << 3;
  unsigned short* hal = (unsigned short*)(lds + HA);
  const int mtile = w & 3, nbase = (w >> 2) * 64;

  f32x4 acc[4];
  #pragma unroll
  for (int nt = 0; nt < 4; ++nt) acc[nt] = f32x4{0.f, 0.f, 0.f, 0.f};

  auto gemm_acc = [&](const unsigned short* Wm) {
    #pragma unroll
    for (int ks = 0; ks < 4; ++ks) {
      short8 a = *(const short8*)(lds + A1 +
                   swzo(mtile * 16 + lm, ks * 64 + g * 16));
      #pragma unroll
      for (int nt = 0; nt < 4; ++nt) {
        int n = nbase + nt * 16 + lm;
        short8 bf = *(const short8*)(Wm + n * 128 + ks * 32 + g * 8);
        acc[nt] = __builtin_amdgcn_mfma_f32_16x16x32_bf16(a, bf, acc[nt], 0, 0, 0);
      }
    }
  };

  // halo of attention output (bf16)
  {
    const unsigned short* src = outb + (size_t)b * CHW_;
    for (int idx = t; idx < 12800; idx += 512) {
      int c = idx / 100, r = idx - c * 100;
      int hy = r / 10, hx = r - hy * 10;
      int gy = y0 - 1 + hy, gx = x0 - 1 + hx;
      unsigned short v = 0;
      if ((unsigned)gy < 128u && (unsigned)gx < 128u)
        v = src[(size_t)c * HW_ + gy * W_ + gx];
      hal[c * 102 + r] = v;
    }
  }
  __syncthreads();
  // strip-mined proj-dw
  #pragma unroll
  for (int it = 0; it < 2; ++it) {
    int u = t + it * 512;
    int c = u & 127, py = u >> 7;
    const float* wp = pdw + c * 9;
    float w0 = wp[0], w1 = wp[1], w2 = wp[2], w3 = wp[3], w4 = wp[4],
          w5 = wp[5], w6 = wp[6], w7 = wp[7], w8 = wp[8];
    float bb = pdb[c];
    float rv[3][10];
    #pragma unroll
    for (int rr = 0; rr < 3; ++rr) {
      const unsigned* rp = (const unsigned*)(hal + c * 102 + (py + rr) * 10);
      #pragma unroll
      for (int e = 0; e < 5; ++e) {
        unsigned pk = rp[e];
        rv[rr][2 * e] = uasf(pk << 16);
        rv[rr][2 * e + 1] = uasf(pk & 0xffff0000u);
      }
    }
    #pragma unroll
    for (int px = 0; px < 8; ++px) {
      float s = rv[0][px] * w0 + rv[0][px + 1] * w1 + rv[0][px + 2] * w2
              + rv[1][px] * w3 + rv[1][px + 1] * w4 + rv[1][px + 2] * w5
              + rv[2][px] * w6 + rv[2][px + 1] * w7 + rv[2][px + 2] * w8;
      *(unsigned short*)(lds + A1 + swzo(py * 8 + px, 2 * c)) = f2b(s + bb);
    }
  }
  __syncthreads();
  gemm_acc(W3);  // folded Wc on proj-dw
  __syncthreads();

  // stage 2: A = x*y (float4 loads; keep y in regs)
  float4 ykeep[4];
  #pragma unroll
  for (int it = 0; it < 4; ++it) {
    int u = t + it * 512;
    int c = u & 127, q4 = u >> 7;
    int py = q4 >> 1, px0 = (q4 & 1) * 4;
    size_t gbase = (size_t)b * CHW_ + (size_t)c * HW_ + (y0 + py) * W_ + x0 + px0;
    float4 xv = *(const float4*)(x + gbase);
    float4 yv = *(const float4*)(y + gbase);
    ykeep[it] = yv;
    const float* xp = (const float*)&xv;
    const float* yp = (const float*)&yv;
    #pragma unroll
    for (int e = 0; e < 4; ++e)
      *(unsigned short*)(lds + A1 + swzo(q4 * 4 + e, 2 * c)) =
          f2b(xp[e] * yp[e]);
  }
  __syncthreads();
  gemm_acc(W3 + 16384);  // fw1
  __syncthreads();
  // stage 3: A = y (ca_y folded into W2b)
  #pragma unroll
  for (int it = 0; it < 4; ++it) {
    int u = t + it * 512;
    int c = u & 127, q4 = u >> 7;
    const float* yp = (const float*)&ykeep[it];
    #pragma unroll
    for (int e = 0; e < 4; ++e)
      *(unsigned short*)(lds + A1 + swzo(q4 * 4 + e, 2 * c)) = f2b(yp[e]);
  }
  __syncthreads();
  gemm_acc(W2b + ((size_t)b << 14));  // fw2 * diag(ca_y)

  // epilogue: bias + BN + ReLU -> fst (pitch 130 f32) -> float4 stores
  float* fst = (float*)(lds + HA);
  #pragma unroll
  for (int nt = 0; nt < 4; ++nt) {
    int ch = nbase + nt * 16 + lm;
    float zb = bc[ch];
    float inv = rsqrtf(bnv[ch] + 1e-5f);
    float gsc = inv * bng[ch];
    float mm = bnm[ch], ab = bnb[ch];
    #pragma unroll
    for (int r2 = 0; r2 < 4; ++r2) {
      int pos = mtile * 16 + g * 4 + r2;
      float z = acc[nt][r2] + zb;
      z = (z - mm) * gsc + ab;
      fst[pos * 130 + ch] = fmaxf(z, 0.f);
    }
  }
  __syncthreads();
  #pragma unroll
  for (int it = 0; it < 4; ++it) {
    int u = t + it * 512;
    int c = u & 127, q4 = u >> 7;
    int py = q4 >> 1, px0 = (q4 & 1) * 4;
    f32x4 ov;
    #pragma unroll
    for (int e = 0; e < 4; ++e) ov[e] = fst[(q4 * 4 + e) * 130 + c];
    *(f32x4*)(outp + (size_t)b * CHW_ + (size_t)c * HW_ +
              (y0 + py) * W_ + x0 + px0) = ov;
  }
}

// ---------------- launcher ----------------
extern "C" void kernel_launch(void* const* d_in, const int* in_sizes, int n_in,
                              void* d_out, int out_size, void* d_ws, size_t ws_size,
                              hipStream_t stream) {
  const float* x       = (const float*)d_in[0];
  const float* y       = (const float*)d_in[1];
  const float* ca_w1   = (const float*)d_in[2];
  const float* ca_b1   = (const float*)d_in[3];
  const float* ca_w2   = (const float*)d_in[4];
  const float* ca_b2   = (const float*)d_in[5];
  const float* final_w = (const float*)d_in[6];
  const float* final_b = (const float*)d_in[7];
  const float* bn_g    = (const float*)d_in[8];
  const float* bn_b    = (const float*)d_in[9];
  const float* bn_m    = (const float*)d_in[10];
  const float* bn_v    = (const float*)d_in[11];
  const float* q_dw_w  = (const float*)d_in[12];
  const float* q_dw_b  = (const float*)d_in[13];
  const float* q_pw_w  = (const float*)d_in[14];
  const float* q_pw_b  = (const float*)d_in[15];
  const float* k_dw_w  = (const float*)d_in[16];
  const float* k_dw_b  = (const float*)d_in[17];
  const float* k_pw_w  = (const float*)d_in[18];
  const float* k_pw_b  = (const float*)d_in[19];
  const float* v_dw_w  = (const float*)d_in[20];
  const float* v_dw_b  = (const float*)d_in[21];
  const float* v_pw_w  = (const float*)d_in[22];
  const float* v_pw_b  = (const float*)d_in[23];
  const float* p_dw_w  = (const float*)d_in[24];
  const float* p_dw_b  = (const float*)d_in[25];
  const float* p_pw_w  = (const float*)d_in[26];
  const float* p_pw_b  = (const float*)d_in[27];

  char* ws = (char*)d_ws;
  float* sums = (float*)(ws + 0);                       // 8 KB
  float* cab  = (float*)(ws + 8192);                    // 8 KB
  unsigned short* Wqkv = (unsigned short*)(ws + 16384); // mats 0..2 (96 KB)
  unsigned short* W3   = Wqkv + 3 * 16384;              // mats 3..5 (96 KB)
  float* bc   = (float*)(ws + 212992);                  // 512 B
  unsigned short* W2b  = (unsigned short*)(ws + 213504);// 8 x 32 KB
  unsigned short* outb = (unsigned short*)(ws + (1 << 20));  // 33.5 MB bf16

  k_pool<<<2048, 256, 0, stream>>>(x, y, sums);
  k_ca<<<8, 256, 0, stream>>>(sums, ca_w1, ca_b1, ca_w2, ca_b2, cab);
  k_prep<<<1792, 128, 0, stream>>>(q_pw_w, k_pw_w, v_pw_w, final_w, final_b,
                                   p_pw_w, p_pw_b, cab, Wqkv, W2b, bc);
  k_qkv_attn<<<2048, 512, 0, stream>>>(x, y, cab,
      q_dw_w, q_dw_b, k_dw_w, k_dw_b, v_dw_w, v_dw_b,
      Wqkv, q_pw_b, k_pw_b, v_pw_b, outb);
  k_final<<<2048, 512, 0, stream>>>(x, y, outb,
      p_dw_w, p_dw_b, W3, W2b, bc,
      bn_g, bn_b, bn_m, bn_v, (float*)d_out);
}

// Round 4
// 360.898 us; speedup vs baseline: 5.4605x; 1.2437x over previous
//
#include <hip/hip_runtime.h>

typedef __attribute__((ext_vector_type(8))) short short8;
typedef __attribute__((ext_vector_type(4))) float f32x4;
typedef __attribute__((ext_vector_type(2))) unsigned u32x2;
typedef __attribute__((ext_vector_type(4))) unsigned u32x4;

static constexpr int C_ = 128, H_ = 128, W_ = 128;
static constexpr int HW_ = H_ * W_;
static constexpr int CHW_ = C_ * HW_;

__device__ __forceinline__ unsigned short f2b(float f) {
  union { float f; unsigned u; } cv; cv.f = f;
  unsigned r = cv.u + 0x7FFFu + ((cv.u >> 16) & 1u);
  return (unsigned short)(r >> 16);
}
__device__ __forceinline__ float b2f(unsigned short h) {
  union { unsigned u; float f; } cv; cv.u = ((unsigned)h) << 16;
  return cv.f;
}
__device__ __forceinline__ float uasf(unsigned u) {
  union { unsigned u; float f; } cv; cv.u = u; return cv.f;
}
// swizzled byte offset within a 64-row x 256B-row LDS tile
__device__ __forceinline__ int swzo(int pos, int byteInRow) {
  return pos * 256 + (byteInRow ^ ((pos & 7) << 4));
}

// ---------------- K1: per-(b, channel-of-concat) sums ----------------
__global__ __launch_bounds__(256) void k_pool(const float* __restrict__ x,
                                              const float* __restrict__ y,
                                              float* __restrict__ sums) {
  int blk = blockIdx.x;
  int b = blk >> 8, c = blk & 255;
  const float* src = (c < C_) ? (x + (size_t)b * CHW_ + (size_t)c * HW_)
                              : (y + (size_t)b * CHW_ + (size_t)(c - C_) * HW_);
  const float4* s4 = (const float4*)src;
  float acc = 0.f;
  for (int i = threadIdx.x; i < HW_ / 4; i += 256) {
    float4 v = s4[i];
    acc += v.x + v.y + v.z + v.w;
  }
  for (int off = 32; off; off >>= 1) acc += __shfl_down(acc, off, 64);
  __shared__ float red[4];
  int lane = threadIdx.x & 63, wv = threadIdx.x >> 6;
  if (lane == 0) red[wv] = acc;
  __syncthreads();
  if (threadIdx.x == 0) sums[blk] = red[0] + red[1] + red[2] + red[3];
}

// ---------------- K2: channel attention ----------------
__global__ __launch_bounds__(256) void k_ca(const float* __restrict__ sums,
                                            const float* __restrict__ w1,
                                            const float* __restrict__ b1,
                                            const float* __restrict__ w2,
                                            const float* __restrict__ b2,
                                            float* __restrict__ ca) {
  int b = blockIdx.x;
  __shared__ float pooled[256];
  __shared__ float hb[16];
  int t = threadIdx.x;
  pooled[t] = sums[b * 256 + t] * (1.f / 16384.f);
  __syncthreads();
  if (t < 16) {
    float s = b1[t];
    for (int j = 0; j < 256; ++j) s += w1[t * 256 + j] * pooled[j];
    hb[t] = fmaxf(s, 0.f);
  }
  __syncthreads();
  float s = b2[t];
  for (int r = 0; r < 16; ++r) s += w2[t * 16 + r] * hb[r];
  ca[b * 256 + t] = 1.f / (1.f + __expf(-s));
}

// ---------------- K3: weight prep ----------------
__global__ __launch_bounds__(128) void k_prep(
    const float* __restrict__ qpw, const float* __restrict__ kpw,
    const float* __restrict__ vpw,
    const float* __restrict__ fw, const float* __restrict__ fb,
    const float* __restrict__ ppw, const float* __restrict__ ppb,
    const float* __restrict__ cab,
    unsigned short* __restrict__ Wb, unsigned short* __restrict__ W2b,
    float* __restrict__ bc) {
  int blk = blockIdx.x, c = threadIdx.x;
  if (blk < 768) {
    int mat = blk >> 7, o = blk & 127;
    float v = 0.f;
    if (mat == 0) v = qpw[o * 128 + c];
    else if (mat == 1) v = kpw[o * 128 + c];
    else if (mat == 2) v = vpw[o * 128 + c];
    else if (mat == 3) {
      float a = 0.f;
      for (int m = 0; m < 128; ++m) a += fw[o * 384 + 256 + m] * ppw[m * 128 + c];
      v = a;
      if (c == 0) {
        float bb = fb[o];
        for (int m = 0; m < 128; ++m) bb += fw[o * 384 + 256 + m] * ppb[m];
        bc[o] = bb;
      }
    } else if (mat == 4) v = fw[o * 384 + c];
    else v = 0.f;
    Wb[((size_t)mat << 14) + o * 128 + c] = f2b(v);
  } else {
    int bb = (blk - 768) >> 7, o = blk & 127;
    W2b[((size_t)bb << 14) + o * 128 + c] =
        f2b(fw[o * 384 + 128 + c] * cab[bb * 256 + 128 + c]);
  }
}

// ---------------- K4: fused dw + MFMA pw q/k/v + MFMA window attention ------
// 16x4 spatial tiles. LDS: QS[0,16K) KS[16K,32K) VT[32K,48K) A1[48K,64K)
// A2[64K,80K). halo (768 rows x 18 u16 = 27.6K) aliases [16K,44K);
// scr aliases A1; OS aliases A2.
__global__ __launch_bounds__(512, 4) void k_qkv_attn(
    const float* __restrict__ x, const float* __restrict__ y,
    const float* __restrict__ cab,
    const float* __restrict__ qdw, const float* __restrict__ qdb,
    const float* __restrict__ kdw, const float* __restrict__ kdb,
    const float* __restrict__ vdw, const float* __restrict__ vdb,
    const unsigned short* __restrict__ Wqkv,
    const float* __restrict__ qpb, const float* __restrict__ kpb,
    const float* __restrict__ vpb,
    unsigned short* __restrict__ outb) {
  __shared__ __align__(16) char lds[81920];
  constexpr int QS = 0, KS = 16384, VT = 32768, A1 = 49152, A2 = 65536;
  constexpr int HA = 16384, SCR = 49152, OS = 65536;

  const int t = threadIdx.x;
  const int l = t & 63;
  const int w = t >> 6;
  const int lm = l & 15, g = l >> 4;
  const int bs = ((blockIdx.x & 7) << 8) | (blockIdx.x >> 3);  // XCD-chunked
  const int b = bs >> 8, tr = bs & 255;
  const int y0 = (tr >> 3) << 2, x0 = (tr & 7) << 4;
  const int ct = t & 127, rowt = t >> 7;
  unsigned short* hal = (unsigned short*)(lds + HA);  // [hrow][c] pitch 18 u16

  // ---- halo row loader: 768 tasks (6 hrows x 128 ch), 6 f32x4 chunks each
  auto halo_issue = [&](const float* src, f32x4 (*hv)[6]) {
    #pragma unroll
    for (int tk = 0; tk < 2; ++tk) {
      int task = t + tk * 512;
      bool tv = task < 768;
      int c = task & 127, hr = task >> 7;
      int gy = y0 - 1 + hr;
      bool rowok = tv && ((unsigned)gy < 128u);
      const float* rsrc = src + (size_t)c * HW_ + gy * W_;
      #pragma unroll
      for (int ck = 0; ck < 6; ++ck) {
        int gxc = x0 - 4 + 4 * ck;
        bool ok = rowok && ((unsigned)gxc < 125u);
        hv[tk][ck] = ok ? *(const f32x4*)(rsrc + gxc) : f32x4{0.f, 0.f, 0.f, 0.f};
      }
    }
  };
  // f[m] <-> gx = x0-4+m ; store i=0..17 <-> gx = x0-1+i  (m = i+3)
  auto halo_write = [&](const f32x4 (*hv)[6]) {
    #pragma unroll
    for (int tk = 0; tk < 2; ++tk) {
      int task = t + tk * 512;
      if (task < 768) {
        int base = ((task >> 7) * 128 + (task & 127)) * 18;
        const float* f = (const float*)hv[tk];
        #pragma unroll
        for (int e = 0; e < 9; ++e) {
          unsigned u = (unsigned)f2b(f[2 * e + 3]) |
                       ((unsigned)f2b(f[2 * e + 4]) << 16);
          *(unsigned*)(hal + base + 2 * e) = u;
        }
      }
    }
  };

  // ---- strip-mined dw: thread = (c, py), 16-wide output row
  auto dw_one = [&](const float* wdw, const float* bdw, const float* cas,
                    int aOff) {
    const float* wp = wdw + ct * 9;
    float wr[9];
    #pragma unroll
    for (int k2 = 0; k2 < 9; ++k2) wr[k2] = wp[k2];
    float cam = cas[ct], bb = bdw[ct];
    float o[16];
    #pragma unroll
    for (int px = 0; px < 16; ++px) o[px] = 0.f;
    #pragma unroll
    for (int rr = 0; rr < 3; ++rr) {
      int base = ((rowt + rr) * 128 + ct) * 18;
      unsigned rp[9];
      #pragma unroll
      for (int e = 0; e < 9; ++e) rp[e] = *(const unsigned*)(hal + base + 2 * e);
      float rv[18];
      #pragma unroll
      for (int e = 0; e < 9; ++e) {
        rv[2 * e] = uasf(rp[e] << 16);
        rv[2 * e + 1] = uasf(rp[e] & 0xffff0000u);
      }
      #pragma unroll
      for (int px = 0; px < 16; ++px)
        o[px] += rv[px] * wr[3 * rr] + rv[px + 1] * wr[3 * rr + 1] +
                 rv[px + 2] * wr[3 * rr + 2];
    }
    #pragma unroll
    for (int px = 0; px < 16; ++px)
      *(unsigned short*)(lds + aOff + swzo(rowt * 16 + px, 2 * ct)) =
          f2b(o[px] * cam + bb);
  };
  auto dw_kv = [&](const float* kw, const float* kb2, const float* vw,
                   const float* vb2, const float* cas) {
    const float* kp = kw + ct * 9;
    const float* vp = vw + ct * 9;
    float wk[9], wv2[9];
    #pragma unroll
    for (int k2 = 0; k2 < 9; ++k2) { wk[k2] = kp[k2]; wv2[k2] = vp[k2]; }
    float cam = cas[ct], kbb = kb2[ct], vbb = vb2[ct];
    float ok[16], ov[16];
    #pragma unroll
    for (int px = 0; px < 16; ++px) { ok[px] = 0.f; ov[px] = 0.f; }
    #pragma unroll
    for (int rr = 0; rr < 3; ++rr) {
      int base = ((rowt + rr) * 128 + ct) * 18;
      unsigned rp[9];
      #pragma unroll
      for (int e = 0; e < 9; ++e) rp[e] = *(const unsigned*)(hal + base + 2 * e);
      float rv[18];
      #pragma unroll
      for (int e = 0; e < 9; ++e) {
        rv[2 * e] = uasf(rp[e] << 16);
        rv[2 * e + 1] = uasf(rp[e] & 0xffff0000u);
      }
      #pragma unroll
      for (int px = 0; px < 16; ++px) {
        ok[px] += rv[px] * wk[3 * rr] + rv[px + 1] * wk[3 * rr + 1] +
                  rv[px + 2] * wk[3 * rr + 2];
        ov[px] += rv[px] * wv2[3 * rr] + rv[px + 1] * wv2[3 * rr + 1] +
                  rv[px + 2] * wv2[3 * rr + 2];
      }
    }
    #pragma unroll
    for (int px = 0; px < 16; ++px) {
      int so = swzo(rowt * 16 + px, 2 * ct);
      *(unsigned short*)(lds + A1 + so) = f2b(ok[px] * cam + kbb);
      *(unsigned short*)(lds + A2 + so) = f2b(ov[px] * cam + vbb);
    }
  };

  const int mtile = w & 3, nbase = (w >> 2) * 64;

  auto gemm_qk = [&](int aOff, const unsigned short* Wm, const float* bias,
                     int dstOff) {
    f32x4 acc[4];
    #pragma unroll
    for (int nt = 0; nt < 4; ++nt) acc[nt] = f32x4{0.f, 0.f, 0.f, 0.f};
    #pragma unroll
    for (int ks = 0; ks < 4; ++ks) {
      short8 wf[4];
      #pragma unroll
      for (int nt = 0; nt < 4; ++nt)
        wf[nt] = *(const short8*)(Wm + (nbase + nt * 16 + lm) * 128 +
                                  ks * 32 + g * 8);
      short8 a = *(const short8*)(lds + aOff +
                   swzo(mtile * 16 + lm, ks * 64 + g * 16));
      #pragma unroll
      for (int nt = 0; nt < 4; ++nt)
        acc[nt] = __builtin_amdgcn_mfma_f32_16x16x32_bf16(a, wf[nt], acc[nt], 0, 0, 0);
    }
    #pragma unroll
    for (int nt = 0; nt < 4; ++nt) {
      int ch = nbase + nt * 16 + lm;
      float bv = bias[ch];
      #pragma unroll
      for (int r2 = 0; r2 < 4; ++r2) {
        int pos = mtile * 16 + g * 4 + r2;
        *(unsigned short*)(lds + dstOff + swzo(pos, 2 * ch)) =
            f2b(acc[nt][r2] + bv);
      }
    }
  };
  // V gemm -> transposed window-major tile VT[ch][col ^ ((ch&7)<<3)]
  // pos = mtile*16 + g*4 + r2 -> win = g, n = mtile*4 + r2
  auto gemm_v = [&](int aOff, const unsigned short* Wm, const float* bias) {
    f32x4 acc[4];
    #pragma unroll
    for (int nt = 0; nt < 4; ++nt) acc[nt] = f32x4{0.f, 0.f, 0.f, 0.f};
    #pragma unroll
    for (int ks = 0; ks < 4; ++ks) {
      short8 wf[4];
      #pragma unroll
      for (int nt = 0; nt < 4; ++nt)
        wf[nt] = *(const short8*)(Wm + (nbase + nt * 16 + lm) * 128 +
                                  ks * 32 + g * 8);
      short8 a = *(const short8*)(lds + aOff +
                   swzo(mtile * 16 + lm, ks * 64 + g * 16));
      #pragma unroll
      for (int nt = 0; nt < 4; ++nt)
        acc[nt] = __builtin_amdgcn_mfma_f32_16x16x32_bf16(a, wf[nt], acc[nt], 0, 0, 0);
    }
    #pragma unroll
    for (int nt = 0; nt < 4; ++nt) {
      int ch = nbase + nt * 16 + lm;
      float bv = bias[ch];
      int col = (g * 16 + mtile * 4) ^ ((ch & 7) << 3);
      unsigned lo = (unsigned)f2b(acc[nt][0] + bv) |
                    ((unsigned)f2b(acc[nt][1] + bv) << 16);
      unsigned hi = (unsigned)f2b(acc[nt][2] + bv) |
                    ((unsigned)f2b(acc[nt][3] + bv) << 16);
      *(u32x2*)(lds + VT + ch * 128 + 2 * col) = u32x2{lo, hi};
    }
  };

  const float* cax = cab + b * 256;
  const float* cay = cax + 128;

  // 1. issue y-halo; 2. issue x-halo; 3. write y-halo
  f32x4 hy[2][6], hx[2][6];
  halo_issue(y + (size_t)b * CHW_, hy);
  halo_issue(x + (size_t)b * CHW_, hx);
  halo_write(hy);
  __syncthreads();
  dw_one(qdw, qdb, cay, A1);          // x-halo loads still in flight
  __syncthreads();
  halo_write(hx);                     // halo region free (y reads done)
  gemm_qk(A1, Wqkv, qpb, QS);
  __syncthreads();
  dw_kv(kdw, kdb, vdw, vdb, cax);
  __syncthreads();
  gemm_qk(A1, Wqkv + 16384, kpb, KS); // KS aliases dead halo
  gemm_v(A2, Wqkv + 32768, vpb);
  __syncthreads();

  // ---- MFMA window attention: wave = head, 4 windows sequential ----
  {
    const int h = w;
    const int chb = h * 32;
    char* scr = lds + SCR + w * 512;
    const short8 zz = {};
    #pragma unroll
    for (int wi = 0; wi < 4; ++wi) {
      int rowp = (lm >> 2) * 16 + wi * 4 + (lm & 3);
      short8 av = zz, bv = zz;
      if (g < 2) {
        av = *(const short8*)(lds + KS + swzo(rowp, chb + g * 16));
        bv = *(const short8*)(lds + QS + swzo(rowp, chb + g * 16));
      }
      f32x4 st = __builtin_amdgcn_mfma_f32_16x16x32_bf16(
          av, bv, f32x4{0.f, 0.f, 0.f, 0.f}, 0, 0, 0);
      float s0 = st[0] * 0.25f, s1 = st[1] * 0.25f,
            s2 = st[2] * 0.25f, s3 = st[3] * 0.25f;
      float mx = fmaxf(fmaxf(s0, s1), fmaxf(s2, s3));
      mx = fmaxf(mx, __shfl_xor(mx, 16, 64));
      mx = fmaxf(mx, __shfl_xor(mx, 32, 64));
      float e0 = __expf(s0 - mx), e1 = __expf(s1 - mx),
            e2 = __expf(s2 - mx), e3 = __expf(s3 - mx);
      float sm = e0 + e1 + e2 + e3;
      sm += __shfl_xor(sm, 16, 64);
      sm += __shfl_xor(sm, 32, 64);
      float rl = 1.f / sm;
      unsigned p0 = (unsigned)f2b(e0 * rl) | ((unsigned)f2b(e1 * rl) << 16);
      unsigned p1 = (unsigned)f2b(e2 * rl) | ((unsigned)f2b(e3 * rl) << 16);
      *(u32x2*)(scr + lm * 32 + g * 8) = u32x2{p0, p1};
      short8 pb2 = zz, va = zz;
      if (g < 2) {
        pb2 = *(const short8*)(scr + lm * 32 + g * 16);
        int ch = h * 16 + lm;
        va = *(const short8*)(lds + VT + ch * 128 +
                              2 * ((wi * 16 + g * 8) ^ ((ch & 7) << 3)));
      }
      f32x4 ot = __builtin_amdgcn_mfma_f32_16x16x32_bf16(
          va, pb2, f32x4{0.f, 0.f, 0.f, 0.f}, 0, 0, 0);
      unsigned o0 = (unsigned)f2b(ot[0]) | ((unsigned)f2b(ot[1]) << 16);
      unsigned o1 = (unsigned)f2b(ot[2]) | ((unsigned)f2b(ot[3]) << 16);
      *(u32x2*)(lds + OS + swzo(rowp, chb + g * 8)) = u32x2{o0, o1};
    }
  }
  __syncthreads();
  {
    unsigned short* dst = outb + (size_t)b * CHW_ + (size_t)ct * HW_ +
                          (y0 + rowt) * W_ + x0;
    unsigned v[8];
    #pragma unroll
    for (int j = 0; j < 8; ++j) {
      unsigned lo = *(const unsigned short*)(lds + OS + swzo(rowt * 16 + 2 * j, 2 * ct));
      unsigned hi = *(const unsigned short*)(lds + OS + swzo(rowt * 16 + 2 * j + 1, 2 * ct));
      v[j] = lo | (hi << 16);
    }
    *(u32x4*)(dst) = u32x4{v[0], v[1], v[2], v[3]};
    *(u32x4*)(dst + 8) = u32x4{v[4], v[5], v[6], v[7]};
  }
}

// ---------------- K5: proj-dw + 3 accumulated MFMA GEMMs + BN + ReLU --------
// 16x4 tiles. LDS: A1[0,16K), halo (768 x 22 u16 = 33.8K) / fst alias at 16K.
__global__ __launch_bounds__(512, 4) void k_final(
    const float* __restrict__ x, const float* __restrict__ y,
    const unsigned short* __restrict__ outb,
    const float* __restrict__ pdw, const float* __restrict__ pdb,
    const unsigned short* __restrict__ W3,
    const unsigned short* __restrict__ W2b,
    const float* __restrict__ bc,
    const float* __restrict__ bng, const float* __restrict__ bnb,
    const float* __restrict__ bnm, const float* __restrict__ bnv,
    float* __restrict__ outp) {
  __shared__ __align__(16) char lds[50176];
  constexpr int A1 = 0, HA = 16384;

  const int t = threadIdx.x, l = t & 63, w = t >> 6;
  const int lm = l & 15, g = l >> 4;
  const int bs = ((blockIdx.x & 7) << 8) | (blockIdx.x >> 3);
  const int b = bs >> 8, tr = bs & 255;
  const int y0 = (tr >> 3) << 2, x0 = (tr & 7) << 4;
  const int ct = t & 127, rowt = t >> 7;
  unsigned short* hal = (unsigned short*)(lds + HA);  // [hrow][c] pitch 22 u16
  const int mtile = w & 3, nbase = (w >> 2) * 64;

  f32x4 acc[4];
  #pragma unroll
  for (int nt = 0; nt < 4; ++nt) acc[nt] = f32x4{0.f, 0.f, 0.f, 0.f};

  auto gemm_acc = [&](const unsigned short* Wm) {
    #pragma unroll
    for (int ks = 0; ks < 4; ++ks) {
      short8 wf[4];
      #pragma unroll
      for (int nt = 0; nt < 4; ++nt)
        wf[nt] = *(const short8*)(Wm + (nbase + nt * 16 + lm) * 128 +
                                  ks * 32 + g * 8);
      short8 a = *(const short8*)(lds + A1 +
                   swzo(mtile * 16 + lm, ks * 64 + g * 16));
      #pragma unroll
      for (int nt = 0; nt < 4; ++nt)
        acc[nt] = __builtin_amdgcn_mfma_f32_16x16x32_bf16(a, wf[nt], acc[nt], 0, 0, 0);
    }
  };

  // 1. x/y row loads (full 64B lines)
  const size_t gbase = (size_t)b * CHW_ + (size_t)ct * HW_ +
                       (size_t)(y0 + rowt) * W_ + x0;
  f32x4 xv[4], yv[4];
  #pragma unroll
  for (int e = 0; e < 4; ++e) {
    xv[e] = *(const f32x4*)(x + gbase + 4 * e);
    yv[e] = *(const f32x4*)(y + gbase + 4 * e);
  }
  // 2. issue outb halo (u32 pairs, uniform validity): i=0..19 <-> gx=x0-2+i
  unsigned hreg[2][10];
  #pragma unroll
  for (int tk = 0; tk < 2; ++tk) {
    int task = t + tk * 512;
    bool tv = task < 768;
    int c = task & 127, hr = task >> 7;
    int gy = y0 - 1 + hr;
    bool rowok = tv && ((unsigned)gy < 128u);
    const unsigned short* hsrc = outb + (size_t)b * CHW_ + (size_t)c * HW_ + gy * W_;
    #pragma unroll
    for (int e = 0; e < 10; ++e) {
      int gx0 = x0 - 2 + 2 * e;
      bool okp = rowok && ((unsigned)gx0 < 127u);
      hreg[tk][e] = okp ? *(const unsigned*)(hsrc + gx0) : 0u;
    }
  }
  // 3. A1 <- x*y
  #pragma unroll
  for (int e = 0; e < 4; ++e)
    #pragma unroll
    for (int j = 0; j < 4; ++j)
      *(unsigned short*)(lds + A1 + swzo(rowt * 16 + 4 * e + j, 2 * ct)) =
          f2b(xv[e][j] * yv[e][j]);
  // 4. halo regs -> LDS
  #pragma unroll
  for (int tk = 0; tk < 2; ++tk) {
    int task = t + tk * 512;
    if (task < 768) {
      int base = ((task >> 7) * 128 + (task & 127)) * 22;
      #pragma unroll
      for (int e = 0; e < 10; ++e)
        *(unsigned*)(hal + base + 2 * e) = hreg[tk][e];
    }
  }
  __syncthreads();
  gemm_acc(W3 + 16384);                 // fw1 on x*y
  __syncthreads();
  // 5. A1 <- y
  #pragma unroll
  for (int e = 0; e < 4; ++e)
    #pragma unroll
    for (int j = 0; j < 4; ++j)
      *(unsigned short*)(lds + A1 + swzo(rowt * 16 + 4 * e + j, 2 * ct)) =
          f2b(yv[e][j]);
  __syncthreads();
  gemm_acc(W2b + ((size_t)b << 14));    // fw2 * diag(ca_y)
  __syncthreads();
  // 6. proj-dw from halo -> A1
  {
    const float* wp = pdw + ct * 9;
    float wr[9];
    #pragma unroll
    for (int k2 = 0; k2 < 9; ++k2) wr[k2] = wp[k2];
    float bb = pdb[ct];
    float o[16];
    #pragma unroll
    for (int px = 0; px < 16; ++px) o[px] = 0.f;
    #pragma unroll
    for (int rr = 0; rr < 3; ++rr) {
      int base = ((rowt + rr) * 128 + ct) * 22;
      unsigned rp[10];
      #pragma unroll
      for (int e = 0; e < 10; ++e) rp[e] = *(const unsigned*)(hal + base + 2 * e);
      float rv[20];
      #pragma unroll
      for (int e = 0; e < 10; ++e) {
        rv[2 * e] = uasf(rp[e] << 16);
        rv[2 * e + 1] = uasf(rp[e] & 0xffff0000u);
      }
      #pragma unroll
      for (int px = 0; px < 16; ++px)
        o[px] += rv[px + 1] * wr[3 * rr] + rv[px + 2] * wr[3 * rr + 1] +
                 rv[px + 3] * wr[3 * rr + 2];
    }
    #pragma unroll
    for (int px = 0; px < 16; ++px)
      *(unsigned short*)(lds + A1 + swzo(rowt * 16 + px, 2 * ct)) =
          f2b(o[px] + bb);
  }
  __syncthreads();
  gemm_acc(W3);                          // folded Wc
  // epilogue: bias + BN + ReLU -> fst (pitch 130 f32, aliases halo)
  float* fst = (float*)(lds + HA);
  #pragma unroll
  for (int nt = 0; nt < 4; ++nt) {
    int ch = nbase + nt * 16 + lm;
    float zb = bc[ch];
    float inv = rsqrtf(bnv[ch] + 1e-5f);
    float gsc = inv * bng[ch];
    float mm = bnm[ch], ab = bnb[ch];
    #pragma unroll
    for (int r2 = 0; r2 < 4; ++r2) {
      int pos = mtile * 16 + g * 4 + r2;
      float z = acc[nt][r2] + zb;
      z = (z - mm) * gsc + ab;
      fst[pos * 130 + ch] = fmaxf(z, 0.f);
    }
  }
  __syncthreads();
  #pragma unroll
  for (int e4 = 0; e4 < 4; ++e4) {
    f32x4 ov;
    #pragma unroll
    for (int j = 0; j < 4; ++j) ov[j] = fst[(rowt * 16 + e4 * 4 + j) * 130 + ct];
    *(f32x4*)(outp + gbase + 4 * e4) = ov;
  }
}

// ---------------- launcher ----------------
extern "C" void kernel_launch(void* const* d_in, const int* in_sizes, int n_in,
                              void* d_out, int out_size, void* d_ws, size_t ws_size,
                              hipStream_t stream) {
  const float* x       = (const float*)d_in[0];
  const float* y       = (const float*)d_in[1];
  const float* ca_w1   = (const float*)d_in[2];
  const float* ca_b1   = (const float*)d_in[3];
  const float* ca_w2   = (const float*)d_in[4];
  const float* ca_b2   = (const float*)d_in[5];
  const float* final_w = (const float*)d_in[6];
  const float* final_b = (const float*)d_in[7];
  const float* bn_g    = (const float*)d_in[8];
  const float* bn_b    = (const float*)d_in[9];
  const float* bn_m    = (const float*)d_in[10];
  const float* bn_v    = (const float*)d_in[11];
  const float* q_dw_w  = (const float*)d_in[12];
  const float* q_dw_b  = (const float*)d_in[13];
  const float* q_pw_w  = (const float*)d_in[14];
  const float* q_pw_b  = (const float*)d_in[15];
  const float* k_dw_w  = (const float*)d_in[16];
  const float* k_dw_b  = (const float*)d_in[17];
  const float* k_pw_w  = (const float*)d_in[18];
  const float* k_pw_b  = (const float*)d_in[19];
  const float* v_dw_w  = (const float*)d_in[20];
  const float* v_dw_b  = (const float*)d_in[21];
  const float* v_pw_w  = (const float*)d_in[22];
  const float* v_pw_b  = (const float*)d_in[23];
  const float* p_dw_w  = (const float*)d_in[24];
  const float* p_dw_b  = (const float*)d_in[25];
  const float* p_pw_w  = (const float*)d_in[26];
  const float* p_pw_b  = (const float*)d_in[27];

  char* ws = (char*)d_ws;
  float* sums = (float*)(ws + 0);                       // 8 KB
  float* cab  = (float*)(ws + 8192);                    // 8 KB
  unsigned short* Wqkv = (unsigned short*)(ws + 16384); // mats 0..2 (96 KB)
  unsigned short* W3   = Wqkv + 3 * 16384;              // mats 3..5 (96 KB)
  float* bc   = (float*)(ws + 212992);                  // 512 B
  unsigned short* W2b  = (unsigned short*)(ws + 213504);// 8 x 32 KB
  unsigned short* outb = (unsigned short*)(ws + (1 << 20));  // 33.5 MB bf16

  k_pool<<<2048, 256, 0, stream>>>(x, y, sums);
  k_ca<<<8, 256, 0, stream>>>(sums, ca_w1, ca_b1, ca_w2, ca_b2, cab);
  k_prep<<<1792, 128, 0, stream>>>(q_pw_w, k_pw_w, v_pw_w, final_w, final_b,
                                   p_pw_w, p_pw_b, cab, Wqkv, W2b, bc);
  k_qkv_attn<<<2048, 512, 0, stream>>>(x, y, cab,
      q_dw_w, q_dw_b, k_dw_w, k_dw_b, v_dw_w, v_dw_b,
      Wqkv, q_pw_b, k_pw_b, v_pw_b, outb);
  k_final<<<2048, 512, 0, stream>>>(x, y, outb,
      p_dw_w, p_dw_b, W3, W2b, bc,
      bn_g, bn_b, bn_m, bn_v, (float*)d_out);
}